// Round 1
// baseline (316.466 us; speedup 1.0000x reference)
//
#include <hip/hip_runtime.h>
#include <hip/hip_cooperative_groups.h>
#include <math.h>

namespace cg = cooperative_groups;

#define BB 4
#define LL 4096
#define DD 256
#define NROWS (BB*LL)      // 16384
#define CHUNK 32
#define NC (LL/CHUNK)      // 128
#define NB 8192            // counting-sort bins

typedef __bf16 bf16x8 __attribute__((ext_vector_type(8)));
typedef __bf16 bf16x4 __attribute__((ext_vector_type(4)));
typedef float floatx4 __attribute__((ext_vector_type(4)));

// ---------------- K1: partial u = {Wq^T w, Wk^T w} (no atomics/memset) + split Wv ----------------
__global__ void k_prep(const float* __restrict__ Wq, const float* __restrict__ Wk,
                       const float* __restrict__ Wv, const float* __restrict__ w,
                       float* __restrict__ u_part,
                       __bf16* __restrict__ Wh, __bf16* __restrict__ Wl) {
    __shared__ float wl[16];
    int d = threadIdx.x;
    int e0 = blockIdx.x * 16;
    if (d < 16) wl[d] = w[e0 + d];
    __syncthreads();
    float aq = 0.f, ak = 0.f;
    #pragma unroll
    for (int j = 0; j < 16; ++j) {
        float we = wl[j];
        aq = fmaf(Wq[(size_t)(e0 + j)*DD + d], we, aq);
        ak = fmaf(Wk[(size_t)(e0 + j)*DD + d], we, ak);
        float wv = Wv[(size_t)(e0 + j)*DD + d];
        __bf16 h = (__bf16)wv;
        Wh[(size_t)(e0 + j)*DD + d] = h;
        Wl[(size_t)(e0 + j)*DD + d] = (__bf16)(wv - (float)h);
    }
    u_part[(size_t)blockIdx.x*512 + d]       = aq;
    u_part[(size_t)blockIdx.x*512 + DD + d]  = ak;
}

// ---------------- K2: V = x @ Wv^T via split-bf16 MFMA (unchanged, verified) ----------------
__global__ void __launch_bounds__(256) k_gemm_mfma(
        const float* __restrict__ x,
        const __bf16* __restrict__ Wh, const __bf16* __restrict__ Wl,
        const float* __restrict__ u_part, const float* __restrict__ bmlp,
        float* __restrict__ V, float* __restrict__ a, float* __restrict__ c) {
    __shared__ __bf16 Ah[2][32*40];
    __shared__ __bf16 Al[2][32*40];
    __shared__ float4 ul[128];
    __shared__ float pros[512];
    const int tid = threadIdx.x;
    const int wave = tid >> 6, lane = tid & 63;
    const int rowBase = blockIdx.x * 32;
    const int colBase = blockIdx.y * 128;
    const int quad = lane >> 4, l16 = lane & 15;
    const int srow = tid >> 3, skq = (tid & 7) * 4;
    const bool doproj = (blockIdx.y == 0);

    if (doproj && tid < 128) {
        float4 s = make_float4(0.f, 0.f, 0.f, 0.f);
        #pragma unroll
        for (int g = 0; g < 16; ++g) {
            float4 p = *(const float4*)(u_part + (size_t)g*512 + tid*4);
            s.x += p.x; s.y += p.y; s.z += p.z; s.w += p.w;
        }
        ul[tid] = s;
    }
    __syncthreads();

    floatx4 acc[2][2];
    #pragma unroll
    for (int rt = 0; rt < 2; ++rt)
        #pragma unroll
        for (int ct = 0; ct < 2; ++ct)
            acc[rt][ct] = (floatx4){0.f, 0.f, 0.f, 0.f};
    float aq = 0.f, ak = 0.f;

    const float* xrow = x + (size_t)(rowBase + srow)*DD + skq;

    {
        float4 xv = *(const float4*)xrow;
        __bf16 h0 = (__bf16)xv.x, h1 = (__bf16)xv.y, h2 = (__bf16)xv.z, h3 = (__bf16)xv.w;
        bf16x4 hv = {h0, h1, h2, h3};
        bf16x4 lv = {(__bf16)(xv.x - (float)h0), (__bf16)(xv.y - (float)h1),
                     (__bf16)(xv.z - (float)h2), (__bf16)(xv.w - (float)h3)};
        *(bf16x4*)&Ah[0][srow*40 + skq] = hv;
        *(bf16x4*)&Al[0][srow*40 + skq] = lv;
        if (doproj) {
            float4 q4 = ul[(tid & 7)];
            float4 k4 = ul[64 + (tid & 7)];
            aq = fmaf(xv.x, q4.x, fmaf(xv.y, q4.y, fmaf(xv.z, q4.z, fmaf(xv.w, q4.w, aq))));
            ak = fmaf(xv.x, k4.x, fmaf(xv.y, k4.y, fmaf(xv.z, k4.z, fmaf(xv.w, k4.w, ak))));
        }
    }
    __syncthreads();

    for (int t = 0; t < 8; ++t) {
        const int k0 = t * 32;
        const int cur = t & 1;
        float4 xv;
        if (t < 7) xv = *(const float4*)(xrow + k0 + 32);
        bf16x8 ah[2], al[2];
        #pragma unroll
        for (int rt = 0; rt < 2; ++rt) {
            int m = rt*16 + l16;
            ah[rt] = *(bf16x8*)&Ah[cur][m*40 + quad*8];
            al[rt] = *(bf16x8*)&Al[cur][m*40 + quad*8];
        }
        if (t < 7) {
            __bf16 h0 = (__bf16)xv.x, h1 = (__bf16)xv.y, h2 = (__bf16)xv.z, h3 = (__bf16)xv.w;
            bf16x4 hv = {h0, h1, h2, h3};
            bf16x4 lv = {(__bf16)(xv.x - (float)h0), (__bf16)(xv.y - (float)h1),
                         (__bf16)(xv.z - (float)h2), (__bf16)(xv.w - (float)h3)};
            *(bf16x4*)&Ah[cur^1][srow*40 + skq] = hv;
            *(bf16x4*)&Al[cur^1][srow*40 + skq] = lv;
            if (doproj) {
                float4 q4 = ul[((k0 + 32) >> 2) + (tid & 7)];
                float4 k4 = ul[64 + ((k0 + 32) >> 2) + (tid & 7)];
                aq = fmaf(xv.x, q4.x, fmaf(xv.y, q4.y, fmaf(xv.z, q4.z, fmaf(xv.w, q4.w, aq))));
                ak = fmaf(xv.x, k4.x, fmaf(xv.y, k4.y, fmaf(xv.z, k4.z, fmaf(xv.w, k4.w, ak))));
            }
        }
        __syncthreads();
        #pragma unroll
        for (int ct = 0; ct < 2; ++ct) {
            int n = colBase + wave*32 + ct*16 + l16;
            bf16x8 bh = *(const bf16x8*)(Wh + (size_t)n*DD + k0 + quad*8);
            bf16x8 bl = *(const bf16x8*)(Wl + (size_t)n*DD + k0 + quad*8);
            #pragma unroll
            for (int rt = 0; rt < 2; ++rt) {
                acc[rt][ct] = __builtin_amdgcn_mfma_f32_16x16x32_bf16(ah[rt], bh, acc[rt][ct], 0, 0, 0);
                acc[rt][ct] = __builtin_amdgcn_mfma_f32_16x16x32_bf16(ah[rt], bl, acc[rt][ct], 0, 0, 0);
                acc[rt][ct] = __builtin_amdgcn_mfma_f32_16x16x32_bf16(al[rt], bh, acc[rt][ct], 0, 0, 0);
            }
        }
    }
    #pragma unroll
    for (int rt = 0; rt < 2; ++rt)
        #pragma unroll
        for (int ct = 0; ct < 2; ++ct)
            #pragma unroll
            for (int i = 0; i < 4; ++i) {
                int row = rowBase + rt*16 + quad*4 + i;
                int col = colBase + wave*32 + ct*16 + l16;
                V[(size_t)row*DD + col] = acc[rt][ct][i];
            }
    if (doproj) {
        __syncthreads();
        pros[tid] = aq;
        pros[256 + tid] = ak;
        __syncthreads();
        if (tid < 32) {
            float sa = 0.f, sc = 0.f;
            #pragma unroll
            for (int j = 0; j < 8; ++j) {
                sa += pros[tid*8 + j];
                sc += pros[256 + tid*8 + j];
            }
            a[rowBase + tid] = sa + bmlp[0];
            c[rowBase + tid] = sc;
        }
    }
}

// ---------------- K3: counting sort of c by value-bin + SE prefix
//  NEW: also bins each output row by the chunk q = binstart[bin(a_i)]>>5 it will
//  read its prefix from (129 bins: q=128 holds rows with k==LL), producing
//  rowrec (a_i, k, kend, i) grouped by chunk and rbs_g (chunk row offsets).
//  The a-side lookup reads hist while it still holds binstart, BEFORE the
//  c-scatter mutates it.
__global__ void __launch_bounds__(1024) k_sortish(const float* __restrict__ c,
        const float* __restrict__ a,
        int* __restrict__ perm,
        float* __restrict__ c_sorted, float* __restrict__ e_sorted,
        float* __restrict__ SE, float* __restrict__ hdr,
        float4* __restrict__ rowrec, int* __restrict__ rbs_g) {
    __shared__ int   hist[NB];
    __shared__ float esl[LL];
    __shared__ float scrf[64];
    __shared__ int   qhist[132];
    __shared__ int   rbs[132];
    int b = blockIdx.x, tid = threadIdx.x;
    int wave = tid >> 6, lane = tid & 63;
    int* scri = (int*)scrf;

    float4 cv = ((const float4*)(c + (size_t)b*LL))[tid];
    float cw[4] = {cv.x, cv.y, cv.z, cv.w};
    float mn = fminf(fminf(cw[0],cw[1]), fminf(cw[2],cw[3]));
    float mx = fmaxf(fmaxf(cw[0],cw[1]), fmaxf(cw[2],cw[3]));
    #pragma unroll
    for (int off = 32; off > 0; off >>= 1) {
        mn = fminf(mn, __shfl_down(mn, off));
        mx = fmaxf(mx, __shfl_down(mx, off));
    }
    if (lane == 0) { scrf[wave] = mn; scrf[32 + wave] = mx; }
    __syncthreads();
    if (wave == 0) {
        float m = (lane < 16) ? scrf[lane]      :  3.4e38f;
        float M = (lane < 16) ? scrf[32 + lane] : -3.4e38f;
        #pragma unroll
        for (int off = 32; off > 0; off >>= 1) {
            m = fminf(m, __shfl_down(m, off));
            M = fmaxf(M, __shfl_down(M, off));
        }
        if (lane == 0) { scrf[0] = m; scrf[1] = M; }
    }
    __syncthreads();
    float cmin = scrf[0], cmax = scrf[1];
    float scale = (float)NB / fmaxf(cmax - cmin, 1e-20f);
    __syncthreads();

    ((int4*)hist)[tid] = make_int4(0,0,0,0);
    ((int4*)hist)[tid + 1024] = make_int4(0,0,0,0);
    if (tid < 132) qhist[tid] = 0;
    __syncthreads();

    int bins[4];
    #pragma unroll
    for (int u = 0; u < 4; ++u) {
        int bi = (int)((cw[u] - cmin) * scale);
        bi = bi < 0 ? 0 : (bi > NB-1 ? NB-1 : bi);
        bins[u] = bi;
        atomicAdd(&hist[bi], 1);
    }
    __syncthreads();

    int loc[8]; int base = 0;
    #pragma unroll
    for (int j = 0; j < 8; ++j) { loc[j] = base; base += hist[tid*8 + j]; }
    int incl = base;
    #pragma unroll
    for (int off = 1; off < 64; off <<= 1) {
        int t = __shfl_up(incl, off);
        if (lane >= off) incl += t;
    }
    if (lane == 63) scri[wave] = incl;
    __syncthreads();
    if (wave == 0) {
        int v = (lane < 16) ? scri[lane] : 0;
        int s = v;
        #pragma unroll
        for (int off = 1; off < 16; off <<= 1) {
            int t = __shfl_up(s, off);
            if (lane >= off) s += t;
        }
        if (lane < 16) scri[lane] = s - v;
    }
    __syncthreads();
    int thread_excl = (incl - base) + scri[wave];
    __syncthreads();
    #pragma unroll
    for (int j = 0; j < 8; ++j) {
        int bs = thread_excl + loc[j];
        hist[tid*8 + j] = bs;   // hist now holds binstart
    }
    if (tid == 0) {
        hdr[b*2 + 0] = cmin;
        hdr[b*2 + 1] = scale;
    }
    __syncthreads();

    // ---- NEW a-side lookup (hist == binstart, not yet mutated) ----
    float4 av = ((const float4*)(a + (size_t)b*LL))[tid];
    float aw[4] = {av.x, av.y, av.z, av.w};
    int qq[4]; float4 rec[4];
    #pragma unroll
    for (int u = 0; u < 4; ++u) {
        float t = (aw[u] - cmin) * scale;
        int ibb = t < 0.f ? 0 : (t >= (float)NB ? NB : (int)t);
        int k   = (ibb == NB)     ? LL : hist[ibb];
        int ke  = (ibb >= NB - 1) ? LL : hist[ibb + 1];
        qq[u] = k >> 5;                  // 0..128
        rec[u] = make_float4(aw[u], __int_as_float(k), __int_as_float(ke),
                             __int_as_float(tid*4 + u));
        atomicAdd(&qhist[qq[u]], 1);
    }
    __syncthreads();   // binstart reads done before scatter mutates hist

    #pragma unroll
    for (int u = 0; u < 4; ++u) {
        int i = tid*4 + u;
        int r = atomicAdd(&hist[bins[u]], 1);
        float e = expf(cmin - cw[u]);
        perm[(size_t)b*LL + r] = i;
        c_sorted[(size_t)b*LL + r] = cw[u];
        e_sorted[(size_t)b*LL + r] = e;
        esl[r] = e;
    }
    __syncthreads();

    // ---- NEW: exclusive scan of 129 q-bins -> rbs ----
    if (wave == 0) {
        int v0 = qhist[2*lane], v1 = qhist[2*lane+1];
        int ps = v0 + v1;
        int qi = ps;
        #pragma unroll
        for (int off = 1; off < 64; off <<= 1) {
            int tu = __shfl_up(qi, off);
            if (lane >= off) qi += tu;
        }
        rbs[2*lane]     = qi - ps;
        rbs[2*lane + 1] = qi - v1;
        if (lane == 63) { rbs[128] = qi; rbs[129] = qi + qhist[128]; }
    }
    __syncthreads();
    if (tid < 129) qhist[tid] = rbs[tid];
    if (tid < 130) rbs_g[b*130 + tid] = rbs[tid];
    __syncthreads();
    #pragma unroll
    for (int u = 0; u < 4; ++u) {
        int r = atomicAdd(&qhist[qq[u]], 1);
        rowrec[(size_t)b*LL + r] = rec[u];
    }

    float le[4]; float s0 = 0.f;
    #pragma unroll
    for (int u = 0; u < 4; ++u) { le[u] = s0; s0 += esl[tid*4 + u]; }
    float fincl = s0;
    #pragma unroll
    for (int off = 1; off < 64; off <<= 1) {
        float t = __shfl_up(fincl, off);
        if (lane >= off) fincl += t;
    }
    if (lane == 63) scrf[wave] = fincl;
    __syncthreads();
    if (wave == 0) {
        float v = (lane < 16) ? scrf[lane] : 0.f;
        float s = v;
        #pragma unroll
        for (int off = 1; off < 16; off <<= 1) {
            float t = __shfl_up(s, off);
            if (lane >= off) s += t;
        }
        if (lane < 16) scrf[lane] = s - v;
    }
    __syncthreads();
    float texcl = (fincl - s0) + scrf[wave];
    #pragma unroll
    for (int u = 0; u < 4; ++u)
        SE[(size_t)b*(LL+1) + tid*4 + u] = texcl + le[u];
    if (tid == 1023) SE[(size_t)b*(LL+1) + LL] = texcl + s0;
}

// ---------------- output phase shared by k_fused and fallback k_outf ----------------
// Builds the 33-entry chunk prefix in LDS from registers, then serves the rows
// grouped into this chunk (block NC-1 also serves the k==LL group, local==32).
// Math is op-for-op identical to the previous k_out.
__device__ __forceinline__ void chunk_out_phase(
    int b, int q, int tid, const float (&vr)[CHUNK], const float* ev_l,
    float* Plds, float* Pelds,
    float* bp_l, float* be_l, float* pt_l, float* pe_l,
    const float* __restrict__ baseP, const float* __restrict__ basePe,
    const float4* __restrict__ rowrec, const int* __restrict__ rbs_g,
    const float* __restrict__ SE, const float* __restrict__ hdr,
    const float* __restrict__ c_sorted, const float* __restrict__ e_sorted,
    const int* __restrict__ perm, const float* __restrict__ V,
    float* __restrict__ out)
{
    {
        size_t o  = ((size_t)b*(NC+1) + q)*DD + tid;
        size_t ot = ((size_t)b*(NC+1) + NC)*DD + tid;
        bp_l[tid] = baseP[o];  be_l[tid] = basePe[o];
        pt_l[tid] = baseP[ot]; pe_l[tid] = basePe[ot];
    }
    float accp = 0.f, acce = 0.f;
    #pragma unroll
    for (int r = 0; r < CHUNK; ++r) {
        Plds[r*DD + tid] = accp; Pelds[r*DD + tid] = acce;
        accp += vr[r]; acce = fmaf(ev_l[r], vr[r], acce);
    }
    Plds[CHUNK*DD + tid] = accp; Pelds[CHUNK*DD + tid] = acce;
    __syncthreads();
    const int wave = tid >> 6, lane = tid & 63;
    const int db = lane * 4;
    const float cmin = hdr[b*2];
    const float4 bp4 = *(const float4*)&bp_l[db];
    const float4 be4 = *(const float4*)&be_l[db];
    const float4 pt4 = *(const float4*)&pt_l[db];
    const int rs = rbs_g[b*130 + q];
    const int re = rbs_g[b*130 + q + ((q == NC-1) ? 2 : 1)];
    for (int t = rs + wave; t < re; t += 4) {
        float4 rr = rowrec[(size_t)b*LL + t];
        float ai = rr.x;
        int k    = __float_as_int(rr.y);
        int kend = __float_as_int(rr.z);
        int i    = __float_as_int(rr.w);
        float alpha = expf(cmin - ai);
        int local = k - q*CHUNK;                    // 0..31 (32 only in block NC-1)
        const float4 pl4 = *(const float4*)&Plds[local*DD + db];
        const float4 pe4 = *(const float4*)&Pelds[local*DD + db];
        float Z = fmaf(alpha, (float)(LL - k), SE[(size_t)b*(LL+1) + k]);
        float4 num;
        num.x = fmaf(alpha, pt4.x - (pl4.x + bp4.x), pe4.x + be4.x);
        num.y = fmaf(alpha, pt4.y - (pl4.y + bp4.y), pe4.y + be4.y);
        num.z = fmaf(alpha, pt4.z - (pl4.z + bp4.z), pe4.z + be4.z);
        num.w = fmaf(alpha, pt4.w - (pl4.w + bp4.w), pe4.w + be4.w);
        for (int r = k; r < kend; ++r) {
            float cr = c_sorted[(size_t)b*LL + r];
            if (cr < ai) {
                float w = e_sorted[(size_t)b*LL + r] - alpha;
                int j = perm[(size_t)b*LL + r];
                float4 v = *(const float4*)(V + ((size_t)b*LL + j)*DD + db);
                num.x = fmaf(w, v.x, num.x);
                num.y = fmaf(w, v.y, num.y);
                num.z = fmaf(w, v.z, num.z);
                num.w = fmaf(w, v.w, num.w);
                Z += w;
            }
        }
        float invZ = 1.f / Z;
        float4 o;
        o.x = num.x * invZ; o.y = num.y * invZ; o.z = num.z * invZ; o.w = num.w * invZ;
        *(float4*)(out + ((size_t)b*LL + i)*DD + db) = o;
    }
}

// ---------------- K4*: fused cooperative totals -> base-scan -> output ----------------
// grid (NC, BB) = 512 blocks x 256 threads, 72 KB LDS -> exactly 2 blocks/CU.
// V-chunk stays in registers across both grid syncs (read once from HBM).
__global__ void __launch_bounds__(256, 2) k_fused(
    const float* __restrict__ V, const int* __restrict__ perm,
    const float* __restrict__ e_sorted, const float* __restrict__ c_sorted,
    const float4* __restrict__ rowrec, const int* __restrict__ rbs_g,
    const float* __restrict__ SE, const float* __restrict__ hdr,
    float* __restrict__ Tp, float* __restrict__ Te,
    float* __restrict__ baseP, float* __restrict__ basePe,
    float* __restrict__ out)
{
    __shared__ float Plds[(CHUNK+1)*DD];
    __shared__ float Pelds[(CHUNK+1)*DD];
    __shared__ float bp_l[DD], be_l[DD], pt_l[DD], pe_l[DD];
    __shared__ float ev_l[CHUNK];
    __shared__ int   pj_l[CHUNK];
    const int q = blockIdx.x, b = blockIdx.y, tid = threadIdx.x;
    if (tid < CHUNK) {
        pj_l[tid] = perm[(size_t)b*LL + q*CHUNK + tid];
        ev_l[tid] = e_sorted[(size_t)b*LL + q*CHUNK + tid];
    }
    __syncthreads();
    float vr[CHUNK];
    #pragma unroll
    for (int r = 0; r < CHUNK; ++r)
        vr[r] = V[((size_t)b*LL + pj_l[r])*DD + tid];
    float sp = 0.f, se = 0.f;
    #pragma unroll
    for (int r = 0; r < CHUNK; ++r) { sp += vr[r]; se = fmaf(ev_l[r], vr[r], se); }
    Tp[((size_t)b*NC + q)*DD + tid] = sp;
    Te[((size_t)b*NC + q)*DD + tid] = se;
    __threadfence();
    cg::grid_group grid = cg::this_grid();
    grid.sync();
    if (q == 0) {   // 4 blocks scan the 128 chunk totals (d = tid)
        float ap = 0.f, ae = 0.f;
        #pragma unroll 8
        for (int i = 0; i < NC; ++i) {
            size_t o  = ((size_t)b*(NC+1) + i)*DD + tid;
            size_t ti = ((size_t)b*NC + i)*DD + tid;
            baseP[o] = ap; basePe[o] = ae;
            ap += Tp[ti]; ae += Te[ti];
        }
        baseP[((size_t)b*(NC+1) + NC)*DD + tid]  = ap;
        basePe[((size_t)b*(NC+1) + NC)*DD + tid] = ae;
    }
    __threadfence();
    grid.sync();
    chunk_out_phase(b, q, tid, vr, ev_l, Plds, Pelds, bp_l, be_l, pt_l, pe_l,
                    baseP, basePe, rowrec, rbs_g, SE, hdr,
                    c_sorted, e_sorted, perm, V, out);
}

// ---------------- fallback path (used only if cooperative launch fails) ----------------
__global__ void __launch_bounds__(256) k_tot(
    const float* __restrict__ V, const int* __restrict__ perm,
    const float* __restrict__ e_sorted,
    float* __restrict__ Tp, float* __restrict__ Te)
{
    __shared__ float ev_l[CHUNK];
    __shared__ int   pj_l[CHUNK];
    const int q = blockIdx.x, b = blockIdx.y, tid = threadIdx.x;
    if (tid < CHUNK) {
        pj_l[tid] = perm[(size_t)b*LL + q*CHUNK + tid];
        ev_l[tid] = e_sorted[(size_t)b*LL + q*CHUNK + tid];
    }
    __syncthreads();
    float sp = 0.f, se = 0.f;
    #pragma unroll
    for (int r = 0; r < CHUNK; ++r) {
        float v = V[((size_t)b*LL + pj_l[r])*DD + tid];
        sp += v; se = fmaf(ev_l[r], v, se);
    }
    Tp[((size_t)b*NC + q)*DD + tid] = sp;
    Te[((size_t)b*NC + q)*DD + tid] = se;
}

__global__ void k_base(const float* __restrict__ Tp, const float* __restrict__ Te,
        float* __restrict__ baseP, float* __restrict__ basePe) {
    int q = blockIdx.x, b = blockIdx.y, d = threadIdx.x;
    float acc = 0.f, acce = 0.f;
    #pragma unroll 8
    for (int i = 0; i < q; ++i) {
        size_t ti = ((size_t)b*NC + i) * DD + d;
        acc += Tp[ti]; acce += Te[ti];
    }
    size_t o = ((size_t)b*(NC+1) + q) * DD + d;
    baseP[o] = acc; basePe[o] = acce;
}

__global__ void __launch_bounds__(256, 2) k_outf(
    const float* __restrict__ V, const int* __restrict__ perm,
    const float* __restrict__ e_sorted, const float* __restrict__ c_sorted,
    const float4* __restrict__ rowrec, const int* __restrict__ rbs_g,
    const float* __restrict__ SE, const float* __restrict__ hdr,
    const float* __restrict__ baseP, const float* __restrict__ basePe,
    float* __restrict__ out)
{
    __shared__ float Plds[(CHUNK+1)*DD];
    __shared__ float Pelds[(CHUNK+1)*DD];
    __shared__ float bp_l[DD], be_l[DD], pt_l[DD], pe_l[DD];
    __shared__ float ev_l[CHUNK];
    __shared__ int   pj_l[CHUNK];
    const int q = blockIdx.x, b = blockIdx.y, tid = threadIdx.x;
    if (tid < CHUNK) {
        pj_l[tid] = perm[(size_t)b*LL + q*CHUNK + tid];
        ev_l[tid] = e_sorted[(size_t)b*LL + q*CHUNK + tid];
    }
    __syncthreads();
    float vr[CHUNK];
    #pragma unroll
    for (int r = 0; r < CHUNK; ++r)
        vr[r] = V[((size_t)b*LL + pj_l[r])*DD + tid];
    chunk_out_phase(b, q, tid, vr, ev_l, Plds, Pelds, bp_l, be_l, pt_l, pe_l,
                    baseP, basePe, rowrec, rbs_g, SE, hdr,
                    c_sorted, e_sorted, perm, V, out);
}

extern "C" void kernel_launch(void* const* d_in, const int* in_sizes, int n_in,
                              void* d_out, int out_size, void* d_ws, size_t ws_size,
                              hipStream_t stream) {
    const float* x  = (const float*)d_in[0];
    const float* Wq = (const float*)d_in[1];
    const float* Wk = (const float*)d_in[2];
    const float* Wv = (const float*)d_in[3];
    const float* wm = (const float*)d_in[4];
    const float* bm = (const float*)d_in[5];
    float* out = (float*)d_out;
    float* ws = (float*)d_ws;

    size_t off = 0;
    auto alloc = [&](size_t n) {      // n in floats
        float* p = ws + off;
        off += (n + 255) & ~(size_t)255;
        return p;
    };
    float* u_part   = alloc(16*512);
    float* a        = alloc(NROWS);
    float* c        = alloc(NROWS);
    float* c_sorted = alloc(NROWS);
    float* e_sorted = alloc(NROWS);
    float* SE       = alloc((size_t)BB*(LL+1));
    int*   perm     = (int*)alloc(NROWS);
    float* hdr      = alloc(2*BB);
    float* V        = alloc((size_t)NROWS*DD);
    float* Tp       = alloc((size_t)BB*NC*DD);
    float* Te       = alloc((size_t)BB*NC*DD);
    float* baseP    = alloc((size_t)BB*(NC+1)*DD);
    float* basePe   = alloc((size_t)BB*(NC+1)*DD);
    float4* rowrec  = (float4*)alloc((size_t)NROWS*4);
    int*   rbs_g    = (int*)alloc(BB*130);
    __bf16* Wh      = (__bf16*)alloc((size_t)DD*DD/2);
    __bf16* Wl      = (__bf16*)alloc((size_t)DD*DD/2);

    hipLaunchKernelGGL(k_prep, dim3(16), dim3(DD), 0, stream, Wq, Wk, Wv, wm, u_part, Wh, Wl);
    hipLaunchKernelGGL(k_gemm_mfma, dim3(NROWS/32, 2), dim3(256), 0, stream,
                       x, Wh, Wl, u_part, bm, V, a, c);
    hipLaunchKernelGGL(k_sortish, dim3(BB), dim3(1024), 0, stream,
                       c, a, perm, c_sorted, e_sorted, SE, hdr, rowrec, rbs_g);

    {
        const float*  Vc    = V;
        const int*    permc = perm;
        const float*  ec    = e_sorted;
        const float*  cc    = c_sorted;
        const float4* rrc   = rowrec;
        const int*    rbc   = rbs_g;
        const float*  SEc   = SE;
        const float*  hc    = hdr;
        float* Tpp = Tp; float* Tee = Te; float* bP = baseP; float* bPe = basePe;
        float* op = out;
        void* kargs[] = { (void*)&Vc, (void*)&permc, (void*)&ec, (void*)&cc,
                          (void*)&rrc, (void*)&rbc, (void*)&SEc, (void*)&hc,
                          (void*)&Tpp, (void*)&Tee, (void*)&bP, (void*)&bPe,
                          (void*)&op };
        hipError_t cerr = hipLaunchCooperativeKernel((const void*)k_fused,
                              dim3(NC, BB), dim3(DD), kargs, 0, stream);
        if (cerr != hipSuccess) {
            // non-cooperative fallback: same math, V re-read once more
            hipLaunchKernelGGL(k_tot, dim3(NC, BB), dim3(DD), 0, stream,
                               V, perm, e_sorted, Tp, Te);
            hipLaunchKernelGGL(k_base, dim3(NC+1, BB), dim3(DD), 0, stream,
                               Tp, Te, baseP, basePe);
            hipLaunchKernelGGL(k_outf, dim3(NC, BB), dim3(DD), 0, stream,
                               V, perm, e_sorted, c_sorted, rowrec, rbs_g,
                               SE, hdr, baseP, basePe, out);
        }
    }
}

// Round 2
// 140.880 us; speedup vs baseline: 2.2463x; 2.2463x over previous
//
#include <hip/hip_runtime.h>
#include <math.h>

#define BB 4
#define LL 4096
#define DD 256
#define NROWS (BB*LL)      // 16384
#define CHUNK 32
#define NC (LL/CHUNK)      // 128
#define NB 8192            // counting-sort bins

typedef __bf16 bf16x8 __attribute__((ext_vector_type(8)));
typedef __bf16 bf16x4 __attribute__((ext_vector_type(4)));
typedef float floatx4 __attribute__((ext_vector_type(4)));

// ---------------- K1: partial u = {Wq^T w, Wk^T w} (no atomics/memset) + split Wv ----------------
__global__ void k_prep(const float* __restrict__ Wq, const float* __restrict__ Wk,
                       const float* __restrict__ Wv, const float* __restrict__ w,
                       float* __restrict__ u_part,
                       __bf16* __restrict__ Wh, __bf16* __restrict__ Wl) {
    __shared__ float wl[16];
    int d = threadIdx.x;
    int e0 = blockIdx.x * 16;
    if (d < 16) wl[d] = w[e0 + d];
    __syncthreads();
    float aq = 0.f, ak = 0.f;
    #pragma unroll
    for (int j = 0; j < 16; ++j) {
        float we = wl[j];
        aq = fmaf(Wq[(size_t)(e0 + j)*DD + d], we, aq);
        ak = fmaf(Wk[(size_t)(e0 + j)*DD + d], we, ak);
        float wv = Wv[(size_t)(e0 + j)*DD + d];
        __bf16 h = (__bf16)wv;
        Wh[(size_t)(e0 + j)*DD + d] = h;
        Wl[(size_t)(e0 + j)*DD + d] = (__bf16)(wv - (float)h);
    }
    u_part[(size_t)blockIdx.x*512 + d]       = aq;
    u_part[(size_t)blockIdx.x*512 + DD + d]  = ak;
}

// ---------------- K2: V = x @ Wv^T via split-bf16 MFMA (unchanged, verified) ----------------
__global__ void __launch_bounds__(256) k_gemm_mfma(
        const float* __restrict__ x,
        const __bf16* __restrict__ Wh, const __bf16* __restrict__ Wl,
        const float* __restrict__ u_part, const float* __restrict__ bmlp,
        float* __restrict__ V, float* __restrict__ a, float* __restrict__ c) {
    __shared__ __bf16 Ah[2][32*40];
    __shared__ __bf16 Al[2][32*40];
    __shared__ float4 ul[128];
    __shared__ float pros[512];
    const int tid = threadIdx.x;
    const int wave = tid >> 6, lane = tid & 63;
    const int rowBase = blockIdx.x * 32;
    const int colBase = blockIdx.y * 128;
    const int quad = lane >> 4, l16 = lane & 15;
    const int srow = tid >> 3, skq = (tid & 7) * 4;
    const bool doproj = (blockIdx.y == 0);

    if (doproj && tid < 128) {
        float4 s = make_float4(0.f, 0.f, 0.f, 0.f);
        #pragma unroll
        for (int g = 0; g < 16; ++g) {
            float4 p = *(const float4*)(u_part + (size_t)g*512 + tid*4);
            s.x += p.x; s.y += p.y; s.z += p.z; s.w += p.w;
        }
        ul[tid] = s;
    }
    __syncthreads();

    floatx4 acc[2][2];
    #pragma unroll
    for (int rt = 0; rt < 2; ++rt)
        #pragma unroll
        for (int ct = 0; ct < 2; ++ct)
            acc[rt][ct] = (floatx4){0.f, 0.f, 0.f, 0.f};
    float aq = 0.f, ak = 0.f;

    const float* xrow = x + (size_t)(rowBase + srow)*DD + skq;

    {
        float4 xv = *(const float4*)xrow;
        __bf16 h0 = (__bf16)xv.x, h1 = (__bf16)xv.y, h2 = (__bf16)xv.z, h3 = (__bf16)xv.w;
        bf16x4 hv = {h0, h1, h2, h3};
        bf16x4 lv = {(__bf16)(xv.x - (float)h0), (__bf16)(xv.y - (float)h1),
                     (__bf16)(xv.z - (float)h2), (__bf16)(xv.w - (float)h3)};
        *(bf16x4*)&Ah[0][srow*40 + skq] = hv;
        *(bf16x4*)&Al[0][srow*40 + skq] = lv;
        if (doproj) {
            float4 q4 = ul[(tid & 7)];
            float4 k4 = ul[64 + (tid & 7)];
            aq = fmaf(xv.x, q4.x, fmaf(xv.y, q4.y, fmaf(xv.z, q4.z, fmaf(xv.w, q4.w, aq))));
            ak = fmaf(xv.x, k4.x, fmaf(xv.y, k4.y, fmaf(xv.z, k4.z, fmaf(xv.w, k4.w, ak))));
        }
    }
    __syncthreads();

    for (int t = 0; t < 8; ++t) {
        const int k0 = t * 32;
        const int cur = t & 1;
        float4 xv;
        if (t < 7) xv = *(const float4*)(xrow + k0 + 32);
        bf16x8 ah[2], al[2];
        #pragma unroll
        for (int rt = 0; rt < 2; ++rt) {
            int m = rt*16 + l16;
            ah[rt] = *(bf16x8*)&Ah[cur][m*40 + quad*8];
            al[rt] = *(bf16x8*)&Al[cur][m*40 + quad*8];
        }
        if (t < 7) {
            __bf16 h0 = (__bf16)xv.x, h1 = (__bf16)xv.y, h2 = (__bf16)xv.z, h3 = (__bf16)xv.w;
            bf16x4 hv = {h0, h1, h2, h3};
            bf16x4 lv = {(__bf16)(xv.x - (float)h0), (__bf16)(xv.y - (float)h1),
                         (__bf16)(xv.z - (float)h2), (__bf16)(xv.w - (float)h3)};
            *(bf16x4*)&Ah[cur^1][srow*40 + skq] = hv;
            *(bf16x4*)&Al[cur^1][srow*40 + skq] = lv;
            if (doproj) {
                float4 q4 = ul[((k0 + 32) >> 2) + (tid & 7)];
                float4 k4 = ul[64 + ((k0 + 32) >> 2) + (tid & 7)];
                aq = fmaf(xv.x, q4.x, fmaf(xv.y, q4.y, fmaf(xv.z, q4.z, fmaf(xv.w, q4.w, aq))));
                ak = fmaf(xv.x, k4.x, fmaf(xv.y, k4.y, fmaf(xv.z, k4.z, fmaf(xv.w, k4.w, ak))));
            }
        }
        __syncthreads();
        #pragma unroll
        for (int ct = 0; ct < 2; ++ct) {
            int n = colBase + wave*32 + ct*16 + l16;
            bf16x8 bh = *(const bf16x8*)(Wh + (size_t)n*DD + k0 + quad*8);
            bf16x8 bl = *(const bf16x8*)(Wl + (size_t)n*DD + k0 + quad*8);
            #pragma unroll
            for (int rt = 0; rt < 2; ++rt) {
                acc[rt][ct] = __builtin_amdgcn_mfma_f32_16x16x32_bf16(ah[rt], bh, acc[rt][ct], 0, 0, 0);
                acc[rt][ct] = __builtin_amdgcn_mfma_f32_16x16x32_bf16(ah[rt], bl, acc[rt][ct], 0, 0, 0);
                acc[rt][ct] = __builtin_amdgcn_mfma_f32_16x16x32_bf16(al[rt], bh, acc[rt][ct], 0, 0, 0);
            }
        }
    }
    #pragma unroll
    for (int rt = 0; rt < 2; ++rt)
        #pragma unroll
        for (int ct = 0; ct < 2; ++ct)
            #pragma unroll
            for (int i = 0; i < 4; ++i) {
                int row = rowBase + rt*16 + quad*4 + i;
                int col = colBase + wave*32 + ct*16 + l16;
                V[(size_t)row*DD + col] = acc[rt][ct][i];
            }
    if (doproj) {
        __syncthreads();
        pros[tid] = aq;
        pros[256 + tid] = ak;
        __syncthreads();
        if (tid < 32) {
            float sa = 0.f, sc = 0.f;
            #pragma unroll
            for (int j = 0; j < 8; ++j) {
                sa += pros[tid*8 + j];
                sc += pros[256 + tid*8 + j];
            }
            a[rowBase + tid] = sa + bmlp[0];
            c[rowBase + tid] = sc;
        }
    }
}

// ---------------- K3: counting sort of c by value-bin + SE prefix + row grouping
// (verified in round 1: rowrec/rbs_g path passed with absmax 0.00098)
__global__ void __launch_bounds__(1024) k_sortish(const float* __restrict__ c,
        const float* __restrict__ a,
        int* __restrict__ perm,
        float* __restrict__ c_sorted, float* __restrict__ e_sorted,
        float* __restrict__ SE, float* __restrict__ hdr,
        float4* __restrict__ rowrec, int* __restrict__ rbs_g) {
    __shared__ int   hist[NB];
    __shared__ float esl[LL];
    __shared__ float scrf[64];
    __shared__ int   qhist[132];
    __shared__ int   rbs[132];
    int b = blockIdx.x, tid = threadIdx.x;
    int wave = tid >> 6, lane = tid & 63;
    int* scri = (int*)scrf;

    float4 cv = ((const float4*)(c + (size_t)b*LL))[tid];
    float cw[4] = {cv.x, cv.y, cv.z, cv.w};
    float mn = fminf(fminf(cw[0],cw[1]), fminf(cw[2],cw[3]));
    float mx = fmaxf(fmaxf(cw[0],cw[1]), fmaxf(cw[2],cw[3]));
    #pragma unroll
    for (int off = 32; off > 0; off >>= 1) {
        mn = fminf(mn, __shfl_down(mn, off));
        mx = fmaxf(mx, __shfl_down(mx, off));
    }
    if (lane == 0) { scrf[wave] = mn; scrf[32 + wave] = mx; }
    __syncthreads();
    if (wave == 0) {
        float m = (lane < 16) ? scrf[lane]      :  3.4e38f;
        float M = (lane < 16) ? scrf[32 + lane] : -3.4e38f;
        #pragma unroll
        for (int off = 32; off > 0; off >>= 1) {
            m = fminf(m, __shfl_down(m, off));
            M = fmaxf(M, __shfl_down(M, off));
        }
        if (lane == 0) { scrf[0] = m; scrf[1] = M; }
    }
    __syncthreads();
    float cmin = scrf[0], cmax = scrf[1];
    float scale = (float)NB / fmaxf(cmax - cmin, 1e-20f);
    __syncthreads();

    ((int4*)hist)[tid] = make_int4(0,0,0,0);
    ((int4*)hist)[tid + 1024] = make_int4(0,0,0,0);
    if (tid < 132) qhist[tid] = 0;
    __syncthreads();

    int bins[4];
    #pragma unroll
    for (int u = 0; u < 4; ++u) {
        int bi = (int)((cw[u] - cmin) * scale);
        bi = bi < 0 ? 0 : (bi > NB-1 ? NB-1 : bi);
        bins[u] = bi;
        atomicAdd(&hist[bi], 1);
    }
    __syncthreads();

    int loc[8]; int base = 0;
    #pragma unroll
    for (int j = 0; j < 8; ++j) { loc[j] = base; base += hist[tid*8 + j]; }
    int incl = base;
    #pragma unroll
    for (int off = 1; off < 64; off <<= 1) {
        int t = __shfl_up(incl, off);
        if (lane >= off) incl += t;
    }
    if (lane == 63) scri[wave] = incl;
    __syncthreads();
    if (wave == 0) {
        int v = (lane < 16) ? scri[lane] : 0;
        int s = v;
        #pragma unroll
        for (int off = 1; off < 16; off <<= 1) {
            int t = __shfl_up(s, off);
            if (lane >= off) s += t;
        }
        if (lane < 16) scri[lane] = s - v;
    }
    __syncthreads();
    int thread_excl = (incl - base) + scri[wave];
    __syncthreads();
    #pragma unroll
    for (int j = 0; j < 8; ++j) {
        int bs = thread_excl + loc[j];
        hist[tid*8 + j] = bs;   // hist now holds binstart
    }
    if (tid == 0) {
        hdr[b*2 + 0] = cmin;
        hdr[b*2 + 1] = scale;
    }
    __syncthreads();

    // a-side lookup (hist == binstart, not yet mutated by scatter)
    float4 av = ((const float4*)(a + (size_t)b*LL))[tid];
    float aw[4] = {av.x, av.y, av.z, av.w};
    int qq[4]; float4 rec[4];
    #pragma unroll
    for (int u = 0; u < 4; ++u) {
        float t = (aw[u] - cmin) * scale;
        int ibb = t < 0.f ? 0 : (t >= (float)NB ? NB : (int)t);
        int k   = (ibb == NB)     ? LL : hist[ibb];
        int ke  = (ibb >= NB - 1) ? LL : hist[ibb + 1];
        qq[u] = k >> 5;                  // 0..128
        rec[u] = make_float4(aw[u], __int_as_float(k), __int_as_float(ke),
                             __int_as_float(tid*4 + u));
        atomicAdd(&qhist[qq[u]], 1);
    }
    __syncthreads();   // binstart reads done before scatter mutates hist

    #pragma unroll
    for (int u = 0; u < 4; ++u) {
        int i = tid*4 + u;
        int r = atomicAdd(&hist[bins[u]], 1);
        float e = expf(cmin - cw[u]);
        perm[(size_t)b*LL + r] = i;
        c_sorted[(size_t)b*LL + r] = cw[u];
        e_sorted[(size_t)b*LL + r] = e;
        esl[r] = e;
    }
    __syncthreads();

    // exclusive scan of 129 q-bins -> rbs
    if (wave == 0) {
        int v0 = qhist[2*lane], v1 = qhist[2*lane+1];
        int ps = v0 + v1;
        int qi = ps;
        #pragma unroll
        for (int off = 1; off < 64; off <<= 1) {
            int tu = __shfl_up(qi, off);
            if (lane >= off) qi += tu;
        }
        rbs[2*lane]     = qi - ps;
        rbs[2*lane + 1] = qi - v1;
        if (lane == 63) { rbs[128] = qi; rbs[129] = qi + qhist[128]; }
    }
    __syncthreads();
    if (tid < 129) qhist[tid] = rbs[tid];
    if (tid < 130) rbs_g[b*130 + tid] = rbs[tid];
    __syncthreads();
    #pragma unroll
    for (int u = 0; u < 4; ++u) {
        int r = atomicAdd(&qhist[qq[u]], 1);
        rowrec[(size_t)b*LL + r] = rec[u];
    }

    float le[4]; float s0 = 0.f;
    #pragma unroll
    for (int u = 0; u < 4; ++u) { le[u] = s0; s0 += esl[tid*4 + u]; }
    float fincl = s0;
    #pragma unroll
    for (int off = 1; off < 64; off <<= 1) {
        float t = __shfl_up(fincl, off);
        if (lane >= off) fincl += t;
    }
    if (lane == 63) scrf[wave] = fincl;
    __syncthreads();
    if (wave == 0) {
        float v = (lane < 16) ? scrf[lane] : 0.f;
        float s = v;
        #pragma unroll
        for (int off = 1; off < 16; off <<= 1) {
            float t = __shfl_up(s, off);
            if (lane >= off) s += t;
        }
        if (lane < 16) scrf[lane] = s - v;
    }
    __syncthreads();
    float texcl = (fincl - s0) + scrf[wave];
    #pragma unroll
    for (int u = 0; u < 4; ++u)
        SE[(size_t)b*(LL+1) + tid*4 + u] = texcl + le[u];
    if (tid == 1023) SE[(size_t)b*(LL+1) + LL] = texcl + s0;
}

// ---------------- output phase (verified round 1 inside k_fused) ----------------
// Builds the 33-entry chunk prefix in LDS from registers, then serves the rows
// grouped into this chunk (block NC-1 also serves the k==LL group, local==32).
__device__ __forceinline__ void chunk_out_phase(
    int b, int q, int tid, const float (&vr)[CHUNK], const float* ev_l,
    float* Plds, float* Pelds,
    float* bp_l, float* be_l, float* pt_l, float* pe_l,
    const float* __restrict__ baseP, const float* __restrict__ basePe,
    const float4* __restrict__ rowrec, const int* __restrict__ rbs_g,
    const float* __restrict__ SE, const float* __restrict__ hdr,
    const float* __restrict__ c_sorted, const float* __restrict__ e_sorted,
    const int* __restrict__ perm, const float* __restrict__ V,
    float* __restrict__ out)
{
    {
        size_t o  = ((size_t)b*(NC+1) + q)*DD + tid;
        size_t ot = ((size_t)b*(NC+1) + NC)*DD + tid;
        bp_l[tid] = baseP[o];  be_l[tid] = basePe[o];
        pt_l[tid] = baseP[ot]; pe_l[tid] = basePe[ot];
    }
    float accp = 0.f, acce = 0.f;
    #pragma unroll
    for (int r = 0; r < CHUNK; ++r) {
        Plds[r*DD + tid] = accp; Pelds[r*DD + tid] = acce;
        accp += vr[r]; acce = fmaf(ev_l[r], vr[r], acce);
    }
    Plds[CHUNK*DD + tid] = accp; Pelds[CHUNK*DD + tid] = acce;
    __syncthreads();
    const int wave = tid >> 6, lane = tid & 63;
    const int db = lane * 4;
    const float cmin = hdr[b*2];
    const float4 bp4 = *(const float4*)&bp_l[db];
    const float4 be4 = *(const float4*)&be_l[db];
    const float4 pt4 = *(const float4*)&pt_l[db];
    const int rs = rbs_g[b*130 + q];
    const int re = rbs_g[b*130 + q + ((q == NC-1) ? 2 : 1)];
    for (int t = rs + wave; t < re; t += 4) {
        float4 rr = rowrec[(size_t)b*LL + t];
        float ai = rr.x;
        int k    = __float_as_int(rr.y);
        int kend = __float_as_int(rr.z);
        int i    = __float_as_int(rr.w);
        float alpha = expf(cmin - ai);
        int local = k - q*CHUNK;                    // 0..31 (32 only in block NC-1)
        const float4 pl4 = *(const float4*)&Plds[local*DD + db];
        const float4 pe4 = *(const float4*)&Pelds[local*DD + db];
        float Z = fmaf(alpha, (float)(LL - k), SE[(size_t)b*(LL+1) + k]);
        float4 num;
        num.x = fmaf(alpha, pt4.x - (pl4.x + bp4.x), pe4.x + be4.x);
        num.y = fmaf(alpha, pt4.y - (pl4.y + bp4.y), pe4.y + be4.y);
        num.z = fmaf(alpha, pt4.z - (pl4.z + bp4.z), pe4.z + be4.z);
        num.w = fmaf(alpha, pt4.w - (pl4.w + bp4.w), pe4.w + be4.w);
        for (int r = k; r < kend; ++r) {
            float cr = c_sorted[(size_t)b*LL + r];
            if (cr < ai) {
                float w = e_sorted[(size_t)b*LL + r] - alpha;
                int j = perm[(size_t)b*LL + r];
                float4 v = *(const float4*)(V + ((size_t)b*LL + j)*DD + db);
                num.x = fmaf(w, v.x, num.x);
                num.y = fmaf(w, v.y, num.y);
                num.z = fmaf(w, v.z, num.z);
                num.w = fmaf(w, v.w, num.w);
                Z += w;
            }
        }
        float invZ = 1.f / Z;
        float4 o;
        o.x = num.x * invZ; o.y = num.y * invZ; o.z = num.z * invZ; o.w = num.w * invZ;
        *(float4*)(out + ((size_t)b*LL + i)*DD + db) = o;
    }
}

// ---------------- K4: chunk totals (V read #1, Pl/Pel never touch HBM) ----------------
__global__ void __launch_bounds__(256) k_tot(
    const float* __restrict__ V, const int* __restrict__ perm,
    const float* __restrict__ e_sorted,
    float* __restrict__ Tp, float* __restrict__ Te)
{
    __shared__ float ev_l[CHUNK];
    __shared__ int   pj_l[CHUNK];
    const int q = blockIdx.x, b = blockIdx.y, tid = threadIdx.x;
    if (tid < CHUNK) {
        pj_l[tid] = perm[(size_t)b*LL + q*CHUNK + tid];
        ev_l[tid] = e_sorted[(size_t)b*LL + q*CHUNK + tid];
    }
    __syncthreads();
    float sp = 0.f, se = 0.f;
    #pragma unroll
    for (int r = 0; r < CHUNK; ++r) {
        float v = V[((size_t)b*LL + pj_l[r])*DD + tid];
        sp += v; se = fmaf(ev_l[r], v, se);
    }
    Tp[((size_t)b*NC + q)*DD + tid] = sp;
    Te[((size_t)b*NC + q)*DD + tid] = se;
}

// ---------------- K5: chunk bases (Tp/Te are 0.26 MB -> L2-hot) ----------------
__global__ void k_base(const float* __restrict__ Tp, const float* __restrict__ Te,
        float* __restrict__ baseP, float* __restrict__ basePe) {
    int q = blockIdx.x, b = blockIdx.y, d = threadIdx.x;
    float acc = 0.f, acce = 0.f;
    #pragma unroll 8
    for (int i = 0; i < q; ++i) {
        size_t ti = ((size_t)b*NC + i) * DD + d;
        acc += Tp[ti]; acce += Te[ti];
    }
    size_t o = ((size_t)b*(NC+1) + q) * DD + d;
    baseP[o] = acc; basePe[o] = acce;
}

// ---------------- K6: grouped output, chunk prefix rebuilt in LDS (V read #2) ----------------
__global__ void __launch_bounds__(256, 2) k_outf(
    const float* __restrict__ V, const int* __restrict__ perm,
    const float* __restrict__ e_sorted, const float* __restrict__ c_sorted,
    const float4* __restrict__ rowrec, const int* __restrict__ rbs_g,
    const float* __restrict__ SE, const float* __restrict__ hdr,
    const float* __restrict__ baseP, const float* __restrict__ basePe,
    float* __restrict__ out)
{
    __shared__ float Plds[(CHUNK+1)*DD];
    __shared__ float Pelds[(CHUNK+1)*DD];
    __shared__ float bp_l[DD], be_l[DD], pt_l[DD], pe_l[DD];
    __shared__ float ev_l[CHUNK];
    __shared__ int   pj_l[CHUNK];
    const int q = blockIdx.x, b = blockIdx.y, tid = threadIdx.x;
    if (tid < CHUNK) {
        pj_l[tid] = perm[(size_t)b*LL + q*CHUNK + tid];
        ev_l[tid] = e_sorted[(size_t)b*LL + q*CHUNK + tid];
    }
    __syncthreads();
    float vr[CHUNK];
    #pragma unroll
    for (int r = 0; r < CHUNK; ++r)
        vr[r] = V[((size_t)b*LL + pj_l[r])*DD + tid];
    chunk_out_phase(b, q, tid, vr, ev_l, Plds, Pelds, bp_l, be_l, pt_l, pe_l,
                    baseP, basePe, rowrec, rbs_g, SE, hdr,
                    c_sorted, e_sorted, perm, V, out);
}

extern "C" void kernel_launch(void* const* d_in, const int* in_sizes, int n_in,
                              void* d_out, int out_size, void* d_ws, size_t ws_size,
                              hipStream_t stream) {
    const float* x  = (const float*)d_in[0];
    const float* Wq = (const float*)d_in[1];
    const float* Wk = (const float*)d_in[2];
    const float* Wv = (const float*)d_in[3];
    const float* wm = (const float*)d_in[4];
    const float* bm = (const float*)d_in[5];
    float* out = (float*)d_out;
    float* ws = (float*)d_ws;

    size_t off = 0;
    auto alloc = [&](size_t n) {      // n in floats
        float* p = ws + off;
        off += (n + 255) & ~(size_t)255;
        return p;
    };
    float* u_part   = alloc(16*512);
    float* a        = alloc(NROWS);
    float* c        = alloc(NROWS);
    float* c_sorted = alloc(NROWS);
    float* e_sorted = alloc(NROWS);
    float* SE       = alloc((size_t)BB*(LL+1));
    int*   perm     = (int*)alloc(NROWS);
    float* hdr      = alloc(2*BB);
    float* V        = alloc((size_t)NROWS*DD);
    float* Tp       = alloc((size_t)BB*NC*DD);
    float* Te       = alloc((size_t)BB*NC*DD);
    float* baseP    = alloc((size_t)BB*(NC+1)*DD);
    float* basePe   = alloc((size_t)BB*(NC+1)*DD);
    float4* rowrec  = (float4*)alloc((size_t)NROWS*4);
    int*   rbs_g    = (int*)alloc(BB*130);
    __bf16* Wh      = (__bf16*)alloc((size_t)DD*DD/2);
    __bf16* Wl      = (__bf16*)alloc((size_t)DD*DD/2);

    hipLaunchKernelGGL(k_prep, dim3(16), dim3(DD), 0, stream, Wq, Wk, Wv, wm, u_part, Wh, Wl);
    hipLaunchKernelGGL(k_gemm_mfma, dim3(NROWS/32, 2), dim3(256), 0, stream,
                       x, Wh, Wl, u_part, bm, V, a, c);
    hipLaunchKernelGGL(k_sortish, dim3(BB), dim3(1024), 0, stream,
                       c, a, perm, c_sorted, e_sorted, SE, hdr, rowrec, rbs_g);
    hipLaunchKernelGGL(k_tot, dim3(NC, BB), dim3(256), 0, stream,
                       V, perm, e_sorted, Tp, Te);
    hipLaunchKernelGGL(k_base, dim3(NC+1, BB), dim3(256), 0, stream,
                       Tp, Te, baseP, basePe);
    hipLaunchKernelGGL(k_outf, dim3(NC, BB), dim3(256), 0, stream,
                       V, perm, e_sorted, c_sorted, rowrec, rbs_g,
                       SE, hdr, baseP, basePe, out);
}